// Round 1
// 1071.190 us; speedup vs baseline: 1.3184x; 1.3184x over previous
//
#include <hip/hip_runtime.h>
#include <hip/hip_bf16.h>

#define NNODES 100000
#define NEDGES 1600000
#define DIM 128
#define EDIM 16

#define SCAN_BLK 1024
#define NB1 ((NNODES + SCAN_BLK - 1) / SCAN_BLK)   // 98

// ---- ws layout (bytes). Total ~8.1 MB ----
#define O_CNT    0u          // int[NNODES]      degree histogram
#define O_RP     409600u     // int[NNODES+1]    row_ptr
#define O_CUR    819200u     // int[NNODES]      fill cursors
#define O_DINV   1228800u    // float[NNODES]    deg^{-1/2}
#define O_PART   1638400u    // int[NB1]         scan partials
#define O_PARTEX 1646592u    // int[NB1]         exclusive partials
#define O_CSR    1703936u    // int[NEDGES]      edge sources grouped by dst

__device__ __forceinline__ float bf_lo(unsigned p) { return __uint_as_float(p << 16); }
__device__ __forceinline__ float bf_hi(unsigned p) { return __uint_as_float(p & 0xFFFF0000u); }

// round-to-nearest-even f32 -> bf16 (as high 16 bits)
__device__ __forceinline__ unsigned rn_bf16(float x) {
    unsigned u = __float_as_uint(x);
    return (u + 0x7FFFu + ((u >> 16) & 1u)) >> 16;
}

__global__ __launch_bounds__(256) void hist_kernel(const int* __restrict__ dst,
                                                   int* __restrict__ cnt) {
    int e = blockIdx.x * 256 + threadIdx.x;
    if (e < NEDGES) atomicAdd(&cnt[dst[e]], 1);
}

// scan_a also produces dinv (it already loads cnt) -- saves a kernel launch.
__global__ __launch_bounds__(256) void scan_a(const int* __restrict__ cnt,
                                              int* __restrict__ rp,
                                              int* __restrict__ part,
                                              float* __restrict__ dinv) {
    __shared__ int s[256];
    const int b = blockIdx.x, t = threadIdx.x;
    const int base = b * SCAN_BLK + t * 4;
    int e0 = (base + 0 < NNODES) ? cnt[base + 0] : 0;
    int e1 = (base + 1 < NNODES) ? cnt[base + 1] : 0;
    int e2 = (base + 2 < NNODES) ? cnt[base + 2] : 0;
    int e3 = (base + 3 < NNODES) ? cnt[base + 3] : 0;
    if (base + 0 < NNODES) dinv[base + 0] = (e0 > 0) ? rsqrtf((float)e0) : 0.0f;
    if (base + 1 < NNODES) dinv[base + 1] = (e1 > 0) ? rsqrtf((float)e1) : 0.0f;
    if (base + 2 < NNODES) dinv[base + 2] = (e2 > 0) ? rsqrtf((float)e2) : 0.0f;
    if (base + 3 < NNODES) dinv[base + 3] = (e3 > 0) ? rsqrtf((float)e3) : 0.0f;
    int sum = e0 + e1 + e2 + e3;
    s[t] = sum;
    __syncthreads();
    for (int off = 1; off < 256; off <<= 1) {
        int x = (t >= off) ? s[t - off] : 0;
        __syncthreads();
        s[t] += x;
        __syncthreads();
    }
    int ex = s[t] - sum;
    if (base + 0 < NNODES) rp[base + 0] = ex;
    if (base + 1 < NNODES) rp[base + 1] = ex + e0;
    if (base + 2 < NNODES) rp[base + 2] = ex + e0 + e1;
    if (base + 3 < NNODES) rp[base + 3] = ex + e0 + e1 + e2;
    if (t == 255) part[b] = s[255];
}

__global__ __launch_bounds__(128) void scan_b(const int* __restrict__ part,
                                              int* __restrict__ partex) {
    __shared__ int sp[128];
    const int t = threadIdx.x;
    int v = (t < NB1) ? part[t] : 0;
    sp[t] = v;
    __syncthreads();
    for (int off = 1; off < 128; off <<= 1) {
        int x = (t >= off) ? sp[t - off] : 0;
        __syncthreads();
        sp[t] += x;
        __syncthreads();
    }
    if (t < NB1) partex[t] = sp[t] - v;
}

__global__ __launch_bounds__(256) void scan_c(int* __restrict__ rp,
                                              int* __restrict__ cur,
                                              const int* __restrict__ partex) {
    const int off = partex[blockIdx.x];
    const int t = threadIdx.x;
#pragma unroll
    for (int u = 0; u < 4; ++u) {
        int idx = blockIdx.x * SCAN_BLK + u * 256 + t;
        if (idx < NNODES) {
            int v = rp[idx] + off;
            rp[idx] = v;
            cur[idx] = v;
        }
    }
    if (blockIdx.x == 0 && t == 0) rp[NNODES] = NEDGES;
}

__global__ __launch_bounds__(256) void fill_kernel(const int* __restrict__ src,
                                                   const int* __restrict__ dst,
                                                   int* __restrict__ cur,
                                                   int* __restrict__ csr) {
    int e = blockIdx.x * 256 + threadIdx.x;
    if (e < NEDGES) {
        int d = dst[e];
        int pos = atomicAdd(&cur[d], 1);
        csr[pos] = src[e];
    }
}

// Gather-aggregate only. One WAVE per node; half-wave (32 lanes) per edge with
// float4 row loads (16B/lane x 32 lanes = full 512B row). Main loop keeps
// 8 edges (4 float4 loads/lane) in flight. No barriers, low VGPR -> high
// occupancy to hide the csr->dinv/nh dependent-load latency.
// Result (scaled by dinv[n]) is written to agg = out_nh; the MLP kernel then
// runs in-place on it.
__global__ __launch_bounds__(256) void agg_kernel(const int* __restrict__ rp,
                                                  const int* __restrict__ csr,
                                                  const float* __restrict__ dinv,
                                                  const float* __restrict__ nh,
                                                  float* __restrict__ agg) {
    const int lane = threadIdx.x & 63;
    const int half = lane >> 5;          // 0: even edges, 1: odd edges
    const int l32  = lane & 31;          // float4 index within the row
    const int wid     = (blockIdx.x * 256 + threadIdx.x) >> 6;
    const int nwaves  = (gridDim.x * 256) >> 6;

    for (int n = wid; n < NNODES; n += nwaves) {
        const int beg = rp[n];
        const int end = rp[n + 1];
        const float dn = dinv[n];
        float ax = 0.0f, ay = 0.0f, az = 0.0f, aw = 0.0f;
        int i = beg;
        for (; i + 8 <= end; i += 8) {
            int s0 = csr[i + 0 + half];
            int s1 = csr[i + 2 + half];
            int s2 = csr[i + 4 + half];
            int s3 = csr[i + 6 + half];
            float w0 = dinv[s0], w1 = dinv[s1], w2 = dinv[s2], w3 = dinv[s3];
            float4 f0 = ((const float4*)(nh + (size_t)s0 * DIM))[l32];
            float4 f1 = ((const float4*)(nh + (size_t)s1 * DIM))[l32];
            float4 f2 = ((const float4*)(nh + (size_t)s2 * DIM))[l32];
            float4 f3 = ((const float4*)(nh + (size_t)s3 * DIM))[l32];
            ax = fmaf(f0.x, w0, ax); ay = fmaf(f0.y, w0, ay);
            az = fmaf(f0.z, w0, az); aw = fmaf(f0.w, w0, aw);
            ax = fmaf(f1.x, w1, ax); ay = fmaf(f1.y, w1, ay);
            az = fmaf(f1.z, w1, az); aw = fmaf(f1.w, w1, aw);
            ax = fmaf(f2.x, w2, ax); ay = fmaf(f2.y, w2, ay);
            az = fmaf(f2.z, w2, az); aw = fmaf(f2.w, w2, aw);
            ax = fmaf(f3.x, w3, ax); ay = fmaf(f3.y, w3, ay);
            az = fmaf(f3.z, w3, az); aw = fmaf(f3.w, w3, aw);
        }
        for (; i + 2 <= end; i += 2) {
            int s0 = csr[i + half];
            float w0 = dinv[s0];
            float4 f0 = ((const float4*)(nh + (size_t)s0 * DIM))[l32];
            ax = fmaf(f0.x, w0, ax); ay = fmaf(f0.y, w0, ay);
            az = fmaf(f0.z, w0, az); aw = fmaf(f0.w, w0, aw);
        }
        if (i < end) {  // odd tail: both halves load the edge, half 1 weighted 0
            int s0 = csr[i];
            float w0 = half ? 0.0f : dinv[s0];
            float4 f0 = ((const float4*)(nh + (size_t)s0 * DIM))[l32];
            ax = fmaf(f0.x, w0, ax); ay = fmaf(f0.y, w0, ay);
            az = fmaf(f0.z, w0, az); aw = fmaf(f0.w, w0, aw);
        }
        // combine the two half-wave partials (lane ^ 32 holds the other parity)
        ax += __shfl_xor(ax, 32);
        ay += __shfl_xor(ay, 32);
        az += __shfl_xor(az, 32);
        aw += __shfl_xor(aw, 32);
        if (half == 0) {
            ((float4*)(agg + (size_t)n * DIM))[l32] =
                make_float4(ax * dn, ay * dn, az * dn, aw * dn);
        }
    }
}

// 2-layer MLP, in-place on io (reads agg row, writes output row; rows are
// block-private so in-place is safe). 128 threads, thread j = feature j.
// 4 nodes per iteration: weight unpack amortized 4x, 4 independent FMA chains.
__global__ __launch_bounds__(128) void mlp_kernel(float* __restrict__ io,
                                                  const float* __restrict__ W1,
                                                  const float* __restrict__ b1,
                                                  const float* __restrict__ W2,
                                                  const float* __restrict__ b2) {
    __shared__ float sA[4][DIM];
    __shared__ float sH[4][DIM];
    const int j = threadIdx.x;

    unsigned w1p[64], w2p[64];
#pragma unroll
    for (int k = 0; k < 64; ++k) {
        w1p[k] = rn_bf16(W1[(2 * k) * DIM + j]) | (rn_bf16(W1[(2 * k + 1) * DIM + j]) << 16);
        w2p[k] = rn_bf16(W2[(2 * k) * DIM + j]) | (rn_bf16(W2[(2 * k + 1) * DIM + j]) << 16);
    }
    const float bias1 = b1[j];
    const float bias2 = b2[j];

    // NNODES % 4 == 0, so n0+3 is always in range.
    for (int n0 = blockIdx.x * 4; n0 < NNODES; n0 += gridDim.x * 4) {
        sA[0][j] = io[(size_t)(n0 + 0) * DIM + j];
        sA[1][j] = io[(size_t)(n0 + 1) * DIM + j];
        sA[2][j] = io[(size_t)(n0 + 2) * DIM + j];
        sA[3][j] = io[(size_t)(n0 + 3) * DIM + j];
        __syncthreads();

        const float4* pA0 = (const float4*)sA[0];
        const float4* pA1 = (const float4*)sA[1];
        const float4* pA2 = (const float4*)sA[2];
        const float4* pA3 = (const float4*)sA[3];
        float a0 = bias1, a1 = bias1, a2 = bias1, a3 = bias1;
#pragma unroll
        for (int k = 0; k < 32; ++k) {
            unsigned q0 = w1p[2 * k], q1 = w1p[2 * k + 1];
            float lo0 = bf_lo(q0), hi0 = bf_hi(q0);
            float lo1 = bf_lo(q1), hi1 = bf_hi(q1);
            float4 v0 = pA0[k], v1 = pA1[k], v2 = pA2[k], v3 = pA3[k];
            a0 = fmaf(v0.x, lo0, a0); a0 = fmaf(v0.y, hi0, a0);
            a0 = fmaf(v0.z, lo1, a0); a0 = fmaf(v0.w, hi1, a0);
            a1 = fmaf(v1.x, lo0, a1); a1 = fmaf(v1.y, hi0, a1);
            a1 = fmaf(v1.z, lo1, a1); a1 = fmaf(v1.w, hi1, a1);
            a2 = fmaf(v2.x, lo0, a2); a2 = fmaf(v2.y, hi0, a2);
            a2 = fmaf(v2.z, lo1, a2); a2 = fmaf(v2.w, hi1, a2);
            a3 = fmaf(v3.x, lo0, a3); a3 = fmaf(v3.y, hi0, a3);
            a3 = fmaf(v3.z, lo1, a3); a3 = fmaf(v3.w, hi1, a3);
        }
        sH[0][j] = fmaxf(a0, 0.0f);
        sH[1][j] = fmaxf(a1, 0.0f);
        sH[2][j] = fmaxf(a2, 0.0f);
        sH[3][j] = fmaxf(a3, 0.0f);
        __syncthreads();

        const float4* pH0 = (const float4*)sH[0];
        const float4* pH1 = (const float4*)sH[1];
        const float4* pH2 = (const float4*)sH[2];
        const float4* pH3 = (const float4*)sH[3];
        a0 = bias2; a1 = bias2; a2 = bias2; a3 = bias2;
#pragma unroll
        for (int k = 0; k < 32; ++k) {
            unsigned q0 = w2p[2 * k], q1 = w2p[2 * k + 1];
            float lo0 = bf_lo(q0), hi0 = bf_hi(q0);
            float lo1 = bf_lo(q1), hi1 = bf_hi(q1);
            float4 v0 = pH0[k], v1 = pH1[k], v2 = pH2[k], v3 = pH3[k];
            a0 = fmaf(v0.x, lo0, a0); a0 = fmaf(v0.y, hi0, a0);
            a0 = fmaf(v0.z, lo1, a0); a0 = fmaf(v0.w, hi1, a0);
            a1 = fmaf(v1.x, lo0, a1); a1 = fmaf(v1.y, hi0, a1);
            a1 = fmaf(v1.z, lo1, a1); a1 = fmaf(v1.w, hi1, a1);
            a2 = fmaf(v2.x, lo0, a2); a2 = fmaf(v2.y, hi0, a2);
            a2 = fmaf(v2.z, lo1, a2); a2 = fmaf(v2.w, hi1, a2);
            a3 = fmaf(v3.x, lo0, a3); a3 = fmaf(v3.y, hi0, a3);
            a3 = fmaf(v3.z, lo1, a3); a3 = fmaf(v3.w, hi1, a3);
        }
        io[(size_t)(n0 + 0) * DIM + j] = a0;
        io[(size_t)(n0 + 1) * DIM + j] = a1;
        io[(size_t)(n0 + 2) * DIM + j] = a2;
        io[(size_t)(n0 + 3) * DIM + j] = a3;
        __syncthreads();   // protect sA/sH reuse next iteration
    }
}

extern "C" void kernel_launch(void* const* d_in, const int* in_sizes, int n_in,
                              void* d_out, int out_size, void* d_ws, size_t ws_size,
                              hipStream_t stream) {
    const float* nh = (const float*)d_in[0];   // f32 [NNODES, DIM]
    const float* eh = (const float*)d_in[1];   // f32 [NEDGES, EDIM]
    const int*   ei = (const int*)d_in[2];     // int32 [2, NEDGES]
    const float* W1 = (const float*)d_in[3];
    const float* b1 = (const float*)d_in[4];
    const float* W2 = (const float*)d_in[5];
    const float* b2 = (const float*)d_in[6];

    char* ws = (char*)d_ws;
    int*   cnt    = (int*)(ws + O_CNT);
    int*   rp     = (int*)(ws + O_RP);
    int*   cur    = (int*)(ws + O_CUR);
    float* dinv   = (float*)(ws + O_DINV);
    int*   part   = (int*)(ws + O_PART);
    int*   partex = (int*)(ws + O_PARTEX);
    int*   csr    = (int*)(ws + O_CSR);

    float* out_nh = (float*)d_out;
    float* out_eh = out_nh + (size_t)NNODES * DIM;

    const int* src = ei;
    const int* dst = ei + NEDGES;

    hipMemsetAsync(cnt, 0, (size_t)NNODES * sizeof(int), stream);

    hist_kernel<<<(NEDGES + 255) / 256, 256, 0, stream>>>(dst, cnt);
    scan_a<<<NB1, 256, 0, stream>>>(cnt, rp, part, dinv);
    scan_b<<<1, 128, 0, stream>>>(part, partex);
    scan_c<<<NB1, 256, 0, stream>>>(rp, cur, partex);
    fill_kernel<<<(NEDGES + 255) / 256, 256, 0, stream>>>(src, dst, cur, csr);
    agg_kernel<<<4096, 256, 0, stream>>>(rp, csr, dinv, nh, out_nh);
    mlp_kernel<<<4096, 128, 0, stream>>>(out_nh, W1, b1, W2, b2);

    hipMemcpyAsync(out_eh, eh, (size_t)NEDGES * EDIM * sizeof(float),
                   hipMemcpyDeviceToDevice, stream);
}

// Round 2
// 603.571 us; speedup vs baseline: 2.3398x; 1.7748x over previous
//
#include <hip/hip_runtime.h>
#include <hip/hip_bf16.h>

#define NNODES 100000
#define NEDGES 1600000
#define DIM 128
#define EDIM 16

#define SCAN_BLK 1024
#define NB1 ((NNODES + SCAN_BLK - 1) / SCAN_BLK)   // 98

// ---- ws layout (bytes). Total ~8.1 MB ----
#define O_CNT    0u          // int[NNODES]      degree histogram (DEAD after scan_a
                             //                  -> reused for packed bf16 weights)
#define O_RP     409600u     // int[NNODES+1]    row_ptr
#define O_CUR    819200u     // int[NNODES]      fill cursors
#define O_DINV   1228800u    // float[NNODES]    deg^{-1/2}
#define O_PART   1638400u    // int[NB1]         scan partials
#define O_PARTEX 1646592u    // int[NB1]         exclusive partials
#define O_CSR    1703936u    // int[NEDGES]      edge sources grouped by dst
// packed weights live in the cnt region after scan_a:
#define O_W1P    O_CNT               // ushort[16384] = 32 KB
#define O_W2P    (O_CNT + 32768u)    // ushort[16384] = 32 KB

typedef __attribute__((ext_vector_type(8))) short bf16x8;
typedef __attribute__((ext_vector_type(4))) float f32x4;

__device__ __forceinline__ float bf_lo(unsigned p) { return __uint_as_float(p << 16); }
__device__ __forceinline__ float bf_hi(unsigned p) { return __uint_as_float(p & 0xFFFF0000u); }

// round-to-nearest-even f32 -> bf16 (as low 16 bits of return)
__device__ __forceinline__ unsigned rn_bf16(float x) {
    unsigned u = __float_as_uint(x);
    return (u + 0x7FFFu + ((u >> 16) & 1u)) >> 16;
}

__global__ __launch_bounds__(256) void hist_kernel(const int* __restrict__ dst,
                                                   int* __restrict__ cnt) {
    int e = blockIdx.x * 256 + threadIdx.x;
    if (e < NEDGES) atomicAdd(&cnt[dst[e]], 1);
}

// scan_a also produces dinv (it already loads cnt) -- saves a kernel launch.
__global__ __launch_bounds__(256) void scan_a(const int* __restrict__ cnt,
                                              int* __restrict__ rp,
                                              int* __restrict__ part,
                                              float* __restrict__ dinv) {
    __shared__ int s[256];
    const int b = blockIdx.x, t = threadIdx.x;
    const int base = b * SCAN_BLK + t * 4;
    int e0 = (base + 0 < NNODES) ? cnt[base + 0] : 0;
    int e1 = (base + 1 < NNODES) ? cnt[base + 1] : 0;
    int e2 = (base + 2 < NNODES) ? cnt[base + 2] : 0;
    int e3 = (base + 3 < NNODES) ? cnt[base + 3] : 0;
    if (base + 0 < NNODES) dinv[base + 0] = (e0 > 0) ? rsqrtf((float)e0) : 0.0f;
    if (base + 1 < NNODES) dinv[base + 1] = (e1 > 0) ? rsqrtf((float)e1) : 0.0f;
    if (base + 2 < NNODES) dinv[base + 2] = (e2 > 0) ? rsqrtf((float)e2) : 0.0f;
    if (base + 3 < NNODES) dinv[base + 3] = (e3 > 0) ? rsqrtf((float)e3) : 0.0f;
    int sum = e0 + e1 + e2 + e3;
    s[t] = sum;
    __syncthreads();
    for (int off = 1; off < 256; off <<= 1) {
        int x = (t >= off) ? s[t - off] : 0;
        __syncthreads();
        s[t] += x;
        __syncthreads();
    }
    int ex = s[t] - sum;
    if (base + 0 < NNODES) rp[base + 0] = ex;
    if (base + 1 < NNODES) rp[base + 1] = ex + e0;
    if (base + 2 < NNODES) rp[base + 2] = ex + e0 + e1;
    if (base + 3 < NNODES) rp[base + 3] = ex + e0 + e1 + e2;
    if (t == 255) part[b] = s[255];
}

__global__ __launch_bounds__(128) void scan_b(const int* __restrict__ part,
                                              int* __restrict__ partex) {
    __shared__ int sp[128];
    const int t = threadIdx.x;
    int v = (t < NB1) ? part[t] : 0;
    sp[t] = v;
    __syncthreads();
    for (int off = 1; off < 128; off <<= 1) {
        int x = (t >= off) ? sp[t - off] : 0;
        __syncthreads();
        sp[t] += x;
        __syncthreads();
    }
    if (t < NB1) partex[t] = sp[t] - v;
}

__global__ __launch_bounds__(256) void scan_c(int* __restrict__ rp,
                                              int* __restrict__ cur,
                                              const int* __restrict__ partex) {
    const int off = partex[blockIdx.x];
    const int t = threadIdx.x;
#pragma unroll
    for (int u = 0; u < 4; ++u) {
        int idx = blockIdx.x * SCAN_BLK + u * 256 + t;
        if (idx < NNODES) {
            int v = rp[idx] + off;
            rp[idx] = v;
            cur[idx] = v;
        }
    }
    if (blockIdx.x == 0 && t == 0) rp[NNODES] = NEDGES;
}

__global__ __launch_bounds__(256) void fill_kernel(const int* __restrict__ src,
                                                   const int* __restrict__ dst,
                                                   int* __restrict__ cur,
                                                   int* __restrict__ csr) {
    int e = blockIdx.x * 256 + threadIdx.x;
    if (e < NEDGES) {
        int d = dst[e];
        int pos = atomicAdd(&cur[d], 1);
        csr[pos] = src[e];
    }
}

// Pack W (f32 [128][128], row = k, col = j) into bf16 MFMA B-fragment order for
// v_mfma_f32_16x16x32_bf16:
//   frag (t=kstep 0..3, c=coltile 0..7, lane 0..63, i 0..7)
//     -> W[32t + 8*(lane>>4) + i][16c + (lane&15)]
//   linear idx = ((t*8 + c)*64 + lane)*8 + i
__global__ __launch_bounds__(256) void wpack_kernel(const float* __restrict__ W1,
                                                    const float* __restrict__ W2,
                                                    ushort* __restrict__ w1p,
                                                    ushort* __restrict__ w2p) {
    int idx = blockIdx.x * 256 + threadIdx.x;     // 0..16383
    int i = idx & 7;
    int l = (idx >> 3) & 63;
    int c = (idx >> 9) & 7;
    int t = (idx >> 12) & 3;
    int k = 32 * t + 8 * (l >> 4) + i;
    int j = 16 * c + (l & 15);
    w1p[idx] = (ushort)rn_bf16(W1[k * DIM + j]);
    w2p[idx] = (ushort)rn_bf16(W2[k * DIM + j]);
}

// Gather-aggregate (unchanged from R1). One wave per node; half-wave per edge,
// float4 row loads, 8 edges in flight, no barriers.
__global__ __launch_bounds__(256) void agg_kernel(const int* __restrict__ rp,
                                                  const int* __restrict__ csr,
                                                  const float* __restrict__ dinv,
                                                  const float* __restrict__ nh,
                                                  float* __restrict__ agg) {
    const int lane = threadIdx.x & 63;
    const int half = lane >> 5;
    const int l32  = lane & 31;
    const int wid     = (blockIdx.x * 256 + threadIdx.x) >> 6;
    const int nwaves  = (gridDim.x * 256) >> 6;

    for (int n = wid; n < NNODES; n += nwaves) {
        const int beg = rp[n];
        const int end = rp[n + 1];
        const float dn = dinv[n];
        float ax = 0.0f, ay = 0.0f, az = 0.0f, aw = 0.0f;
        int i = beg;
        for (; i + 8 <= end; i += 8) {
            int s0 = csr[i + 0 + half];
            int s1 = csr[i + 2 + half];
            int s2 = csr[i + 4 + half];
            int s3 = csr[i + 6 + half];
            float w0 = dinv[s0], w1 = dinv[s1], w2 = dinv[s2], w3 = dinv[s3];
            float4 f0 = ((const float4*)(nh + (size_t)s0 * DIM))[l32];
            float4 f1 = ((const float4*)(nh + (size_t)s1 * DIM))[l32];
            float4 f2 = ((const float4*)(nh + (size_t)s2 * DIM))[l32];
            float4 f3 = ((const float4*)(nh + (size_t)s3 * DIM))[l32];
            ax = fmaf(f0.x, w0, ax); ay = fmaf(f0.y, w0, ay);
            az = fmaf(f0.z, w0, az); aw = fmaf(f0.w, w0, aw);
            ax = fmaf(f1.x, w1, ax); ay = fmaf(f1.y, w1, ay);
            az = fmaf(f1.z, w1, az); aw = fmaf(f1.w, w1, aw);
            ax = fmaf(f2.x, w2, ax); ay = fmaf(f2.y, w2, ay);
            az = fmaf(f2.z, w2, az); aw = fmaf(f2.w, w2, aw);
            ax = fmaf(f3.x, w3, ax); ay = fmaf(f3.y, w3, ay);
            az = fmaf(f3.z, w3, az); aw = fmaf(f3.w, w3, aw);
        }
        for (; i + 2 <= end; i += 2) {
            int s0 = csr[i + half];
            float w0 = dinv[s0];
            float4 f0 = ((const float4*)(nh + (size_t)s0 * DIM))[l32];
            ax = fmaf(f0.x, w0, ax); ay = fmaf(f0.y, w0, ay);
            az = fmaf(f0.z, w0, az); aw = fmaf(f0.w, w0, aw);
        }
        if (i < end) {
            int s0 = csr[i];
            float w0 = half ? 0.0f : dinv[s0];
            float4 f0 = ((const float4*)(nh + (size_t)s0 * DIM))[l32];
            ax = fmaf(f0.x, w0, ax); ay = fmaf(f0.y, w0, ay);
            az = fmaf(f0.z, w0, az); aw = fmaf(f0.w, w0, aw);
        }
        ax += __shfl_xor(ax, 32);
        ay += __shfl_xor(ay, 32);
        az += __shfl_xor(az, 32);
        aw += __shfl_xor(aw, 32);
        if (half == 0) {
            ((float4*)(agg + (size_t)n * DIM))[l32] =
                make_float4(ax * dn, ay * dn, az * dn, aw * dn);
        }
    }
}

// MFMA 2-layer MLP, in-place on x/out (= agg buffer). 512 threads = 8 waves;
// block tile = 128 nodes (wave w owns 16 rows). Weights: bf16 fragments staged
// to LDS (64 KB). Activations: f32 -> hi/lo bf16 split (2 MFMAs) so activation
// precision stays ~f32; only weight bf16 rounding remains (same as before).
// Layer transition + output transpose via per-wave XOR-swizzled LDS tile
// (phys = logical ^ ((row&7)<<4)) -> conflict-free-ish, no extra barriers.
__global__ __launch_bounds__(512) void mlp_mfma(const float* __restrict__ x,
                                                const ushort* __restrict__ w1p,
                                                const ushort* __restrict__ w2p,
                                                const float* __restrict__ b1,
                                                const float* __restrict__ b2,
                                                float* __restrict__ out) {
    __shared__ __align__(16) ushort sW[2][16384];   // 64 KB: packed W1, W2
    __shared__ __align__(16) float  sH[8][2048];    // 64 KB: per-wave 16x128 f32

    const int tid  = threadIdx.x;
    const int lane = tid & 63;
    const int w    = tid >> 6;
    const int m    = lane & 15;     // A row / C col within tile
    const int g    = lane >> 4;     // k-group / C row-group

    // stage packed weights (64 KB, coalesced float4)
    {
        const float4* s1 = (const float4*)w1p;
        const float4* s2 = (const float4*)w2p;
        float4* d1 = (float4*)sW[0];
        float4* d2 = (float4*)sW[1];
        for (int q = tid; q < 2048; q += 512) d1[q] = s1[q];
        for (int q = tid; q < 2048; q += 512) d2[q] = s2[q];
    }

    float bias1[8], bias2[8];
#pragma unroll
    for (int c = 0; c < 8; ++c) { bias1[c] = b1[16 * c + m]; bias2[c] = b2[16 * c + m]; }

    __syncthreads();

    const int rowbase = blockIdx.x * 128 + w * 16;
    char* hbase = (char*)sH[w];
    const int node = rowbase + m;
    const bool valid = (node < NNODES);

    // ---------------- layer 1: acc = X @ W1 ----------------
    f32x4 acc[8];
#pragma unroll
    for (int c = 0; c < 8; ++c) acc[c] = f32x4{0.f, 0.f, 0.f, 0.f};

#pragma unroll
    for (int t = 0; t < 4; ++t) {
        const int kb = 32 * t + 8 * g;
        float4 xa = make_float4(0.f, 0.f, 0.f, 0.f);
        float4 xb = make_float4(0.f, 0.f, 0.f, 0.f);
        if (valid) {
            const float4* px = (const float4*)(x + (size_t)node * DIM + kb);
            xa = px[0];
            xb = px[1];
        }
        float v[8] = {xa.x, xa.y, xa.z, xa.w, xb.x, xb.y, xb.z, xb.w};
        bf16x8 ahi, alo;
#pragma unroll
        for (int i = 0; i < 8; ++i) {
            unsigned hu = rn_bf16(v[i]);
            float hf = __uint_as_float(hu << 16);
            ahi[i] = (short)hu;
            alo[i] = (short)rn_bf16(v[i] - hf);
        }
#pragma unroll
        for (int c = 0; c < 8; ++c) {
            bf16x8 bw = *(const bf16x8*)&sW[0][((t * 8 + c) * 64 + lane) * 8];
            acc[c] = __builtin_amdgcn_mfma_f32_16x16x32_bf16(alo, bw, acc[c], 0, 0, 0);
            acc[c] = __builtin_amdgcn_mfma_f32_16x16x32_bf16(ahi, bw, acc[c], 0, 0, 0);
        }
    }

    // bias + relu -> swizzled sH   (C/D: row = 4g + r, col = 16c + m)
#pragma unroll
    for (int c = 0; c < 8; ++c) {
#pragma unroll
        for (int r = 0; r < 4; ++r) {
            int row = 4 * g + r;
            float hv = fmaxf(acc[c][r] + bias1[c], 0.0f);
            int off = (row * 512 + (16 * c + m) * 4) ^ ((row & 7) << 4);
            *(float*)(hbase + off) = hv;
        }
    }

    // ---------------- layer 2: acc = relu(h) @ W2 ----------------
#pragma unroll
    for (int c = 0; c < 8; ++c) acc[c] = f32x4{0.f, 0.f, 0.f, 0.f};

#pragma unroll
    for (int t = 0; t < 4; ++t) {
        const int kb = 32 * t + 8 * g;
        int o0 = (m * 512 + kb * 4) ^ ((m & 7) << 4);
        int o1 = (m * 512 + kb * 4 + 16) ^ ((m & 7) << 4);
        f32x4 va = *(const f32x4*)(hbase + o0);
        f32x4 vb = *(const f32x4*)(hbase + o1);
        float v[8] = {va[0], va[1], va[2], va[3], vb[0], vb[1], vb[2], vb[3]};
        bf16x8 ahi, alo;
#pragma unroll
        for (int i = 0; i < 8; ++i) {
            unsigned hu = rn_bf16(v[i]);
            float hf = __uint_as_float(hu << 16);
            ahi[i] = (short)hu;
            alo[i] = (short)rn_bf16(v[i] - hf);
        }
#pragma unroll
        for (int c = 0; c < 8; ++c) {
            bf16x8 bw = *(const bf16x8*)&sW[1][((t * 8 + c) * 64 + lane) * 8];
            acc[c] = __builtin_amdgcn_mfma_f32_16x16x32_bf16(alo, bw, acc[c], 0, 0, 0);
            acc[c] = __builtin_amdgcn_mfma_f32_16x16x32_bf16(ahi, bw, acc[c], 0, 0, 0);
        }
    }

    // bias -> swizzled sH, then coalesced f32x4 store (2 rows x 512B per instr)
#pragma unroll
    for (int c = 0; c < 8; ++c) {
#pragma unroll
        for (int r = 0; r < 4; ++r) {
            int row = 4 * g + r;
            int off = (row * 512 + (16 * c + m) * 4) ^ ((row & 7) << 4);
            *(float*)(hbase + off) = acc[c][r] + bias2[c];
        }
    }

#pragma unroll
    for (int it = 0; it < 8; ++it) {
        int row = 2 * it + (lane >> 5);
        int c4  = lane & 31;
        int off = (row * 512 + c4 * 16) ^ ((row & 7) << 4);
        f32x4 val = *(const f32x4*)(hbase + off);
        int nodeS = rowbase + row;
        if (nodeS < NNODES)
            *(f32x4*)(out + (size_t)nodeS * DIM + (size_t)c4 * 4) = val;
    }
}

extern "C" void kernel_launch(void* const* d_in, const int* in_sizes, int n_in,
                              void* d_out, int out_size, void* d_ws, size_t ws_size,
                              hipStream_t stream) {
    const float* nh = (const float*)d_in[0];   // f32 [NNODES, DIM]
    const float* eh = (const float*)d_in[1];   // f32 [NEDGES, EDIM]
    const int*   ei = (const int*)d_in[2];     // int32 [2, NEDGES]
    const float* W1 = (const float*)d_in[3];
    const float* b1 = (const float*)d_in[4];
    const float* W2 = (const float*)d_in[5];
    const float* b2 = (const float*)d_in[6];

    char* ws = (char*)d_ws;
    int*    cnt    = (int*)(ws + O_CNT);
    int*    rp     = (int*)(ws + O_RP);
    int*    cur    = (int*)(ws + O_CUR);
    float*  dinv   = (float*)(ws + O_DINV);
    int*    part   = (int*)(ws + O_PART);
    int*    partex = (int*)(ws + O_PARTEX);
    int*    csr    = (int*)(ws + O_CSR);
    ushort* w1p    = (ushort*)(ws + O_W1P);   // overlays cnt (dead after scan_a)
    ushort* w2p    = (ushort*)(ws + O_W2P);

    float* out_nh = (float*)d_out;
    float* out_eh = out_nh + (size_t)NNODES * DIM;

    const int* src = ei;
    const int* dst = ei + NEDGES;

    hipMemsetAsync(cnt, 0, (size_t)NNODES * sizeof(int), stream);

    hist_kernel<<<(NEDGES + 255) / 256, 256, 0, stream>>>(dst, cnt);
    scan_a<<<NB1, 256, 0, stream>>>(cnt, rp, part, dinv);
    // cnt is dead now -> pack weights into its storage
    wpack_kernel<<<64, 256, 0, stream>>>(W1, W2, w1p, w2p);
    scan_b<<<1, 128, 0, stream>>>(part, partex);
    scan_c<<<NB1, 256, 0, stream>>>(rp, cur, partex);
    fill_kernel<<<(NEDGES + 255) / 256, 256, 0, stream>>>(src, dst, cur, csr);
    agg_kernel<<<4096, 256, 0, stream>>>(rp, csr, dinv, nh, out_nh);
    mlp_mfma<<<(NNODES + 127) / 128, 512, 0, stream>>>(out_nh, w1p, w2p, b1, b2, out_nh);

    hipMemcpyAsync(out_eh, eh, (size_t)NEDGES * EDIM * sizeof(float),
                   hipMemcpyDeviceToDevice, stream);
}

// Round 3
// 466.711 us; speedup vs baseline: 3.0259x; 1.2932x over previous
//
#include <hip/hip_runtime.h>
#include <hip/hip_bf16.h>

#define NNODES 100000
#define NEDGES 1600000
#define DIM 128
#define EDIM 16

// ---- coarse bucketing for CSR build ----
#define NBKT 256
#define BW 391            // bucket node-range width: 256*391 = 100096 >= NNODES
#define CHUNK 4096        // edges per bscatter block
#define EPT 16            // CHUNK / 256
#define NCHUNK ((NEDGES + CHUNK - 1) / CHUNK)   // 391

// ---- ws layout (bytes). Total ~13.8 MB ----
#define O_BH     0u          // int[256]       bucket histogram
#define O_BOFS   4096u       // int[257]       bucket offsets (exclusive scan)
#define O_BTAIL  8192u       // int[256]       bucket fill cursors
#define O_W1P    16384u      // ushort[16384]  packed bf16 W1 (32 KB)
#define O_W2P    49152u      // ushort[16384]  packed bf16 W2 (32 KB)
#define O_RP     81920u      // int[NNODES+1]  row_ptr
#define O_DINV   491520u     // float[NNODES]  deg^{-1/2}
#define O_CSR    921600u     // int[NEDGES]    edge sources grouped by dst (6.4 MB)
#define O_EBUF   7340032u    // u32[NEDGES]    bucket-grouped packed records (6.4 MB)

typedef __attribute__((ext_vector_type(8))) short bf16x8;
typedef __attribute__((ext_vector_type(4))) float f32x4;

// round-to-nearest-even f32 -> bf16 (as low 16 bits of return)
__device__ __forceinline__ unsigned rn_bf16(float x) {
    unsigned u = __float_as_uint(x);
    return (u + 0x7FFFu + ((u >> 16) & 1u)) >> 16;
}

// ---------------- CSR build: coarse bucket histogram ----------------
__global__ __launch_bounds__(256) void bhist(const int* __restrict__ dst,
                                             int* __restrict__ bh) {
    __shared__ int s[NBKT];
    s[threadIdx.x] = 0;
    __syncthreads();
    for (int e = blockIdx.x * 256 + threadIdx.x; e < NEDGES; e += gridDim.x * 256)
        atomicAdd(&s[dst[e] / BW], 1);
    __syncthreads();
    atomicAdd(&bh[threadIdx.x], s[threadIdx.x]);
}

__global__ __launch_bounds__(256) void bscan(const int* __restrict__ bh,
                                             int* __restrict__ bofs,
                                             int* __restrict__ btail) {
    __shared__ int s[256];
    const int t = threadIdx.x;
    int v = bh[t];
    s[t] = v;
    __syncthreads();
    for (int off = 1; off < 256; off <<= 1) {
        int x = (t >= off) ? s[t - off] : 0;
        __syncthreads();
        s[t] += x;
        __syncthreads();
    }
    int ex = s[t] - v;
    bofs[t] = ex;
    btail[t] = ex;
    if (t == 255) bofs[256] = s[255];
}

// Scatter edges into bucket-grouped ebuf with LDS-ordered, run-coalesced writes.
// Record: src (17 bits) | dst_local (9 bits) << 17.
__global__ __launch_bounds__(256) void bscatter(const int* __restrict__ src,
                                                const int* __restrict__ dst,
                                                int* __restrict__ btail,
                                                unsigned* __restrict__ ebuf) {
    __shared__ int lcnt[NBKT], lofs[NBKT], lcur[NBKT], gbase[NBKT];
    __shared__ unsigned obuf[CHUNK];
    __shared__ unsigned char qb[CHUNK];
    const int tid = threadIdx.x;
    const int e0 = blockIdx.x * CHUNK;
    const int n = min(CHUNK, NEDGES - e0);

    lcnt[tid] = 0;
    __syncthreads();

    int myb[EPT];
    unsigned myrec[EPT];
#pragma unroll
    for (int k = 0; k < EPT; ++k) {
        int q = k * 256 + tid;
        if (q < n) {
            int e = e0 + q;
            int d = dst[e];
            int bb = d / BW;
            int dl = d - bb * BW;
            myrec[k] = (unsigned)src[e] | ((unsigned)dl << 17);
            myb[k] = bb;
            atomicAdd(&lcnt[bb], 1);
        } else myb[k] = -1;
    }
    __syncthreads();

    const int c = lcnt[tid];
    lofs[tid] = c;
    __syncthreads();
    for (int off = 1; off < 256; off <<= 1) {
        int x = (tid >= off) ? lofs[tid - off] : 0;
        __syncthreads();
        lofs[tid] += x;
        __syncthreads();
    }
    int ex = lofs[tid] - c;      // own slot only: no cross-thread read below
    lofs[tid] = ex;
    lcur[tid] = ex;
    gbase[tid] = atomicAdd(&btail[tid], c);
    __syncthreads();

#pragma unroll
    for (int k = 0; k < EPT; ++k) {
        if (myb[k] >= 0) {
            int p = atomicAdd(&lcur[myb[k]], 1);
            obuf[p] = myrec[k];
            qb[p] = (unsigned char)myb[k];
        }
    }
    __syncthreads();

    // ordered write-out: consecutive q = consecutive positions within a bucket run
    for (int q = tid; q < n; q += 256) {
        int bb = qb[q];
        ebuf[gbase[bb] + (q - lofs[bb])] = obuf[q];
    }
}

// One block per bucket: fine histogram + scan in LDS, write rp/dinv, scatter
// src into the bucket's contiguous (L2-resident) csr window.
__global__ __launch_bounds__(256) void csr_build(const unsigned* __restrict__ ebuf,
                                                 const int* __restrict__ bofs,
                                                 int* __restrict__ rp,
                                                 float* __restrict__ dinv,
                                                 int* __restrict__ csr) {
    __shared__ int fcnt[392];
    __shared__ int fcur[392];
    __shared__ int part[49];
    const int b = blockIdx.x, tid = threadIdx.x;
    const int nodebase = b * BW;
    const int nn = min(BW, NNODES - nodebase);
    const int e0 = bofs[b], e1 = bofs[b + 1];

    for (int i = tid; i < 392; i += 256) fcnt[i] = 0;
    __syncthreads();
    for (int q = e0 + tid; q < e1; q += 256)
        atomicAdd(&fcnt[ebuf[q] >> 17], 1);
    __syncthreads();

    // two-level exclusive scan of fcnt[0..391] in place
    if (tid < 49) {
        int s = 0;
#pragma unroll
        for (int k = 0; k < 8; ++k) {
            int idx = 8 * tid + k;
            if (idx < 392) s += fcnt[idx];
        }
        part[tid] = s;
    }
    __syncthreads();
    if (tid == 0) {
        int s = 0;
        for (int k = 0; k < 49; ++k) { int v = part[k]; part[k] = s; s += v; }
    }
    __syncthreads();
    if (tid < 49) {
        int s = part[tid];
#pragma unroll
        for (int k = 0; k < 8; ++k) {
            int idx = 8 * tid + k;
            if (idx < 392) { int v = fcnt[idx]; fcnt[idx] = s; s += v; }
        }
    }
    __syncthreads();

    // fcnt now holds exclusive prefix; deg_i = fcnt[i+1]-fcnt[i]
    for (int i = tid; i < nn; i += 256) {
        int deg = fcnt[i + 1] - fcnt[i];
        rp[nodebase + i] = e0 + fcnt[i];
        dinv[nodebase + i] = (deg > 0) ? rsqrtf((float)deg) : 0.0f;
        fcur[i] = fcnt[i];
    }
    if (b == NBKT - 1 && tid == 0) rp[NNODES] = NEDGES;
    __syncthreads();

    for (int q = e0 + tid; q < e1; q += 256) {
        unsigned rec = ebuf[q];
        int dl = rec >> 17;
        int pos = atomicAdd(&fcur[dl], 1);
        csr[e0 + pos] = (int)(rec & 0x1FFFFu);
    }
}

// Pack W (f32 [128][128], row = k, col = j) into bf16 MFMA B-fragment order for
// v_mfma_f32_16x16x32_bf16:
//   frag (t=kstep 0..3, c=coltile 0..7, lane 0..63, i 0..7)
//     -> W[32t + 8*(lane>>4) + i][16c + (lane&15)]
__global__ __launch_bounds__(256) void wpack_kernel(const float* __restrict__ W1,
                                                    const float* __restrict__ W2,
                                                    ushort* __restrict__ w1p,
                                                    ushort* __restrict__ w2p) {
    int idx = blockIdx.x * 256 + threadIdx.x;     // 0..16383
    int i = idx & 7;
    int l = (idx >> 3) & 63;
    int c = (idx >> 9) & 7;
    int t = (idx >> 12) & 3;
    int k = 32 * t + 8 * (l >> 4) + i;
    int j = 16 * c + (l & 15);
    w1p[idx] = (ushort)rn_bf16(W1[k * DIM + j]);
    w2p[idx] = (ushort)rn_bf16(W2[k * DIM + j]);
}

// Gather-aggregate (unchanged). One wave per node; half-wave per edge,
// float4 row loads, 8 edges in flight, no barriers.
__global__ __launch_bounds__(256) void agg_kernel(const int* __restrict__ rp,
                                                  const int* __restrict__ csr,
                                                  const float* __restrict__ dinv,
                                                  const float* __restrict__ nh,
                                                  float* __restrict__ agg) {
    const int lane = threadIdx.x & 63;
    const int half = lane >> 5;
    const int l32  = lane & 31;
    const int wid     = (blockIdx.x * 256 + threadIdx.x) >> 6;
    const int nwaves  = (gridDim.x * 256) >> 6;

    for (int n = wid; n < NNODES; n += nwaves) {
        const int beg = rp[n];
        const int end = rp[n + 1];
        const float dn = dinv[n];
        float ax = 0.0f, ay = 0.0f, az = 0.0f, aw = 0.0f;
        int i = beg;
        for (; i + 8 <= end; i += 8) {
            int s0 = csr[i + 0 + half];
            int s1 = csr[i + 2 + half];
            int s2 = csr[i + 4 + half];
            int s3 = csr[i + 6 + half];
            float w0 = dinv[s0], w1 = dinv[s1], w2 = dinv[s2], w3 = dinv[s3];
            float4 f0 = ((const float4*)(nh + (size_t)s0 * DIM))[l32];
            float4 f1 = ((const float4*)(nh + (size_t)s1 * DIM))[l32];
            float4 f2 = ((const float4*)(nh + (size_t)s2 * DIM))[l32];
            float4 f3 = ((const float4*)(nh + (size_t)s3 * DIM))[l32];
            ax = fmaf(f0.x, w0, ax); ay = fmaf(f0.y, w0, ay);
            az = fmaf(f0.z, w0, az); aw = fmaf(f0.w, w0, aw);
            ax = fmaf(f1.x, w1, ax); ay = fmaf(f1.y, w1, ay);
            az = fmaf(f1.z, w1, az); aw = fmaf(f1.w, w1, aw);
            ax = fmaf(f2.x, w2, ax); ay = fmaf(f2.y, w2, ay);
            az = fmaf(f2.z, w2, az); aw = fmaf(f2.w, w2, aw);
            ax = fmaf(f3.x, w3, ax); ay = fmaf(f3.y, w3, ay);
            az = fmaf(f3.z, w3, az); aw = fmaf(f3.w, w3, aw);
        }
        for (; i + 2 <= end; i += 2) {
            int s0 = csr[i + half];
            float w0 = dinv[s0];
            float4 f0 = ((const float4*)(nh + (size_t)s0 * DIM))[l32];
            ax = fmaf(f0.x, w0, ax); ay = fmaf(f0.y, w0, ay);
            az = fmaf(f0.z, w0, az); aw = fmaf(f0.w, w0, aw);
        }
        if (i < end) {
            int s0 = csr[i];
            float w0 = half ? 0.0f : dinv[s0];
            float4 f0 = ((const float4*)(nh + (size_t)s0 * DIM))[l32];
            ax = fmaf(f0.x, w0, ax); ay = fmaf(f0.y, w0, ay);
            az = fmaf(f0.z, w0, az); aw = fmaf(f0.w, w0, aw);
        }
        ax += __shfl_xor(ax, 32);
        ay += __shfl_xor(ay, 32);
        az += __shfl_xor(az, 32);
        aw += __shfl_xor(aw, 32);
        if (half == 0) {
            ((float4*)(agg + (size_t)n * DIM))[l32] =
                make_float4(ax * dn, ay * dn, az * dn, aw * dn);
        }
    }
}

// MFMA 2-layer MLP, in-place on x/out (= agg buffer). 512 threads = 8 waves;
// block tile = 128 nodes (wave w owns 16 rows). Weights: bf16 fragments staged
// to LDS (64 KB). Activations: f32 -> hi/lo bf16 split (2 MFMAs) so activation
// precision stays ~f32; only weight bf16 rounding remains.
__global__ __launch_bounds__(512) void mlp_mfma(const float* __restrict__ x,
                                                const ushort* __restrict__ w1p,
                                                const ushort* __restrict__ w2p,
                                                const float* __restrict__ b1,
                                                const float* __restrict__ b2,
                                                float* __restrict__ out) {
    __shared__ __align__(16) ushort sW[2][16384];   // 64 KB: packed W1, W2
    __shared__ __align__(16) float  sH[8][2048];    // 64 KB: per-wave 16x128 f32

    const int tid  = threadIdx.x;
    const int lane = tid & 63;
    const int w    = tid >> 6;
    const int m    = lane & 15;     // A row / C col within tile
    const int g    = lane >> 4;     // k-group / C row-group

    {
        const float4* s1 = (const float4*)w1p;
        const float4* s2 = (const float4*)w2p;
        float4* d1 = (float4*)sW[0];
        float4* d2 = (float4*)sW[1];
        for (int q = tid; q < 2048; q += 512) d1[q] = s1[q];
        for (int q = tid; q < 2048; q += 512) d2[q] = s2[q];
    }

    float bias1[8], bias2[8];
#pragma unroll
    for (int c = 0; c < 8; ++c) { bias1[c] = b1[16 * c + m]; bias2[c] = b2[16 * c + m]; }

    __syncthreads();

    const int rowbase = blockIdx.x * 128 + w * 16;
    char* hbase = (char*)sH[w];
    const int node = rowbase + m;
    const bool valid = (node < NNODES);

    // ---------------- layer 1: acc = X @ W1 ----------------
    f32x4 acc[8];
#pragma unroll
    for (int c = 0; c < 8; ++c) acc[c] = f32x4{0.f, 0.f, 0.f, 0.f};

#pragma unroll
    for (int t = 0; t < 4; ++t) {
        const int kb = 32 * t + 8 * g;
        float4 xa = make_float4(0.f, 0.f, 0.f, 0.f);
        float4 xb = make_float4(0.f, 0.f, 0.f, 0.f);
        if (valid) {
            const float4* px = (const float4*)(x + (size_t)node * DIM + kb);
            xa = px[0];
            xb = px[1];
        }
        float v[8] = {xa.x, xa.y, xa.z, xa.w, xb.x, xb.y, xb.z, xb.w};
        bf16x8 ahi, alo;
#pragma unroll
        for (int i = 0; i < 8; ++i) {
            unsigned hu = rn_bf16(v[i]);
            float hf = __uint_as_float(hu << 16);
            ahi[i] = (short)hu;
            alo[i] = (short)rn_bf16(v[i] - hf);
        }
#pragma unroll
        for (int c = 0; c < 8; ++c) {
            bf16x8 bw = *(const bf16x8*)&sW[0][((t * 8 + c) * 64 + lane) * 8];
            acc[c] = __builtin_amdgcn_mfma_f32_16x16x32_bf16(alo, bw, acc[c], 0, 0, 0);
            acc[c] = __builtin_amdgcn_mfma_f32_16x16x32_bf16(ahi, bw, acc[c], 0, 0, 0);
        }
    }

    // bias + relu -> swizzled sH   (C/D: row = 4g + r, col = 16c + m)
#pragma unroll
    for (int c = 0; c < 8; ++c) {
#pragma unroll
        for (int r = 0; r < 4; ++r) {
            int row = 4 * g + r;
            float hv = fmaxf(acc[c][r] + bias1[c], 0.0f);
            int off = (row * 512 + (16 * c + m) * 4) ^ ((row & 7) << 4);
            *(float*)(hbase + off) = hv;
        }
    }

    // ---------------- layer 2: acc = relu(h) @ W2 ----------------
#pragma unroll
    for (int c = 0; c < 8; ++c) acc[c] = f32x4{0.f, 0.f, 0.f, 0.f};

#pragma unroll
    for (int t = 0; t < 4; ++t) {
        const int kb = 32 * t + 8 * g;
        int o0 = (m * 512 + kb * 4) ^ ((m & 7) << 4);
        int o1 = (m * 512 + kb * 4 + 16) ^ ((m & 7) << 4);
        f32x4 va = *(const f32x4*)(hbase + o0);
        f32x4 vb = *(const f32x4*)(hbase + o1);
        float v[8] = {va[0], va[1], va[2], va[3], vb[0], vb[1], vb[2], vb[3]};
        bf16x8 ahi, alo;
#pragma unroll
        for (int i = 0; i < 8; ++i) {
            unsigned hu = rn_bf16(v[i]);
            float hf = __uint_as_float(hu << 16);
            ahi[i] = (short)hu;
            alo[i] = (short)rn_bf16(v[i] - hf);
        }
#pragma unroll
        for (int c = 0; c < 8; ++c) {
            bf16x8 bw = *(const bf16x8*)&sW[1][((t * 8 + c) * 64 + lane) * 8];
            acc[c] = __builtin_amdgcn_mfma_f32_16x16x32_bf16(alo, bw, acc[c], 0, 0, 0);
            acc[c] = __builtin_amdgcn_mfma_f32_16x16x32_bf16(ahi, bw, acc[c], 0, 0, 0);
        }
    }

    // bias -> swizzled sH, then coalesced f32x4 store
#pragma unroll
    for (int c = 0; c < 8; ++c) {
#pragma unroll
        for (int r = 0; r < 4; ++r) {
            int row = 4 * g + r;
            int off = (row * 512 + (16 * c + m) * 4) ^ ((row & 7) << 4);
            *(float*)(hbase + off) = acc[c][r] + bias2[c];
        }
    }

#pragma unroll
    for (int it = 0; it < 8; ++it) {
        int row = 2 * it + (lane >> 5);
        int c4  = lane & 31;
        int off = (row * 512 + c4 * 16) ^ ((row & 7) << 4);
        f32x4 val = *(const f32x4*)(hbase + off);
        int nodeS = rowbase + row;
        if (nodeS < NNODES)
            *(f32x4*)(out + (size_t)nodeS * DIM + (size_t)c4 * 4) = val;
    }
}

extern "C" void kernel_launch(void* const* d_in, const int* in_sizes, int n_in,
                              void* d_out, int out_size, void* d_ws, size_t ws_size,
                              hipStream_t stream) {
    const float* nh = (const float*)d_in[0];   // f32 [NNODES, DIM]
    const float* eh = (const float*)d_in[1];   // f32 [NEDGES, EDIM]
    const int*   ei = (const int*)d_in[2];     // int32 [2, NEDGES]
    const float* W1 = (const float*)d_in[3];
    const float* b1 = (const float*)d_in[4];
    const float* W2 = (const float*)d_in[5];
    const float* b2 = (const float*)d_in[6];

    char* ws = (char*)d_ws;
    int*      bh    = (int*)(ws + O_BH);
    int*      bofs  = (int*)(ws + O_BOFS);
    int*      btail = (int*)(ws + O_BTAIL);
    ushort*   w1p   = (ushort*)(ws + O_W1P);
    ushort*   w2p   = (ushort*)(ws + O_W2P);
    int*      rp    = (int*)(ws + O_RP);
    float*    dinv  = (float*)(ws + O_DINV);
    int*      csr   = (int*)(ws + O_CSR);
    unsigned* ebuf  = (unsigned*)(ws + O_EBUF);

    float* out_nh = (float*)d_out;
    float* out_eh = out_nh + (size_t)NNODES * DIM;

    const int* src = ei;
    const int* dst = ei + NEDGES;

    hipMemsetAsync(bh, 0, NBKT * sizeof(int), stream);

    bhist<<<256, 256, 0, stream>>>(dst, bh);
    bscan<<<1, 256, 0, stream>>>(bh, bofs, btail);
    wpack_kernel<<<64, 256, 0, stream>>>(W1, W2, w1p, w2p);
    bscatter<<<NCHUNK, 256, 0, stream>>>(src, dst, btail, ebuf);
    csr_build<<<NBKT, 256, 0, stream>>>(ebuf, bofs, rp, dinv, csr);
    agg_kernel<<<4096, 256, 0, stream>>>(rp, csr, dinv, nh, out_nh);
    mlp_mfma<<<(NNODES + 127) / 128, 512, 0, stream>>>(out_nh, w1p, w2p, b1, b2, out_nh);

    hipMemcpyAsync(out_eh, eh, (size_t)NEDGES * EDIM * sizeof(float),
                   hipMemcpyDeviceToDevice, stream);
}